// Round 8
// baseline (290.583 us; speedup 1.0000x reference)
//
#include <hip/hip_runtime.h>
#include <hip/hip_bf16.h>

#define NN 4096
#define FIN 128
#define FOUT 64
#define NH 8
#define KS 4          // K splits (1024 keys per block)

typedef float f32x4 __attribute__((ext_vector_type(4)));
typedef _Float16 f16x8 __attribute__((ext_vector_type(8)));
typedef _Float16 h2 __attribute__((ext_vector_type(2)));
typedef unsigned long long u64;

static __device__ __forceinline__ h2 as_h2(unsigned u) { return __builtin_bit_cast(h2, u); }
static __device__ __forceinline__ unsigned as_u32(h2 v) { return __builtin_bit_cast(unsigned, v); }

// spread16->64: bit i -> bit 4i (scalar u64 ops -> SALU, off the VALU pipe)
static __device__ __forceinline__ u64 spread4(u64 x) {
    x = (x | (x << 24)) & 0x000000FF000000FFull;
    x = (x | (x << 12)) & 0x000F000F000F000Full;
    x = (x | (x << 6))  & 0x0303030303030303ull;
    x = (x | (x << 3))  & 0x1111111111111111ull;
    return x;
}

// ---------------- K0: fused mask + Wc. Mask role: float4 loads (16B/lane, peak-BW
// regime; stride 256 floats/iter = exactly the wave's read width), 4 ballots per iter,
// scalar bit-spread assembles 4 mask words. (Validated in R6/R7.)
__global__ __launch_bounds__(256) void maskwc_kernel(
    const float* __restrict__ topo, u64* __restrict__ mb,
    const float* __restrict__ proj, const float* __restrict__ score_src,
    const float* __restrict__ score_dst, const float* __restrict__ skip_w,
    float* __restrict__ Wc) {
    const int tid = threadIdx.x;
    if (blockIdx.x < 2048) {               // ---- mask role
        const int wg = blockIdx.x * 4 + (tid >> 6);   // wave 0..8191
        const int lane = tid & 63;
        const size_t base = (size_t)wg * 32;          // 32 mask words per wave
        const float* tp = topo + base * 64 + lane * 4;
#pragma unroll
        for (int it = 0; it < 8; ++it) {
            float4 v = *(const float4*)(tp + it * 256);    // 256 floats per wave-iter
            u64 b0 = __ballot(v.x > -0.5e9f);
            u64 b1 = __ballot(v.y > -0.5e9f);
            u64 b2 = __ballot(v.z > -0.5e9f);
            u64 b3 = __ballot(v.w > -0.5e9f);
            // word g (lanes 16g..16g+15): bit 4*li+c = bc[16g+li]
            u64 wv[4];
#pragma unroll
            for (int g = 0; g < 4; ++g) {
                u64 x0 = spread4((b0 >> (16 * g)) & 0xFFFFu);
                u64 x1 = spread4((b1 >> (16 * g)) & 0xFFFFu);
                u64 x2 = spread4((b2 >> (16 * g)) & 0xFFFFu);
                u64 x3 = spread4((b3 >> (16 * g)) & 0xFFFFu);
                wv[g] = x0 | (x1 << 1) | (x2 << 2) | (x3 << 3);
            }
            if (lane == 0) {
                ulonglong2 s01; s01.x = wv[0]; s01.y = wv[1];
                ulonglong2 s23; s23.x = wv[2]; s23.y = wv[3];
                *(ulonglong2*)&mb[base + it * 4] = s01;
                *(ulonglong2*)&mb[base + it * 4 + 2] = s23;
            }
        }
        return;
    }
    // ---- wc role
    int idx = (blockIdx.x - 2048) * 256 + tid;
    if (idx >= FIN * 80) return;
    int i = idx / 80, c = idx % 80;
    float v = 0.f;
    if (c < 16) {
        int h = c & 7;
        const float* w = (c < 8 ? score_src : score_dst) + h * FOUT;
        const float* p = proj + (size_t)h * FIN * FOUT + (size_t)i * FOUT;
        for (int f = 0; f < FOUT; ++f) v += p[f] * w[f];
    } else {
        int f = c - 16;
        for (int h = 0; h < NH; ++h) v += skip_w[(size_t)(h * FOUT + f) * FIN + i];
        v *= 0.125f;
    }
    Wc[i * 80 + c] = v;
}

// ---------------- K1: x@Wc -> skipm (in d_out), E/F fp16 planes, Cc packed fp16, xb fp16
// C1,C2 pre-scaled by 1/8 (per-row constant, cancels exactly in the softmax ratio) so
// all fp16 products C1*E, C2*F stay far below 65504 (bound ~600 at 1.5x sigma margin).
__global__ __launch_bounds__(256) void scores_kernel(
    const float* __restrict__ x, const float* __restrict__ Wc,
    float* __restrict__ skipm, _Float16* __restrict__ Eh, _Float16* __restrict__ Fh,
    unsigned* __restrict__ Cc, _Float16* __restrict__ xb) {
    __shared__ float wcs[FIN][80];
    __shared__ float xs[16][FIN + 5];
    const int n0 = blockIdx.x * 16;
    const int tid = threadIdx.x;
    for (int i = tid; i < FIN * 80 / 4; i += 256)
        ((float4*)&wcs[0][0])[i] = ((const float4*)Wc)[i];
    const float4* xsrc = (const float4*)(x + (size_t)n0 * FIN);
    for (int i = tid; i < 16 * FIN / 4; i += 256) {
        int r = i >> 5, c4 = i & 31;
        *(float4*)&xs[r][c4 * 4] = xsrc[i];
    }
    __syncthreads();
    const int r = tid & 15;
    const int g = tid >> 4;
    float acc[4];
    float sa = 0.f;
#pragma unroll
    for (int j = 0; j < 4; ++j) acc[j] = 0.f;
#pragma unroll 4
    for (int i = 0; i < FIN; ++i) {
        float xv = xs[r][i];
        float4 p = *(float4*)&wcs[i][16 + g * 4];
        float qv = wcs[i][g];
        acc[0] += xv * p.x; acc[1] += xv * p.y; acc[2] += xv * p.z; acc[3] += xv * p.w;
        sa += xv * qv;
    }
    int n = n0 + r;
#pragma unroll
    for (int j = 0; j < 4; ++j) skipm[(size_t)n * FOUT + g * 4 + j] = acc[j];
    if (g < 8) {
        _Float16 c1 = (_Float16)(expf(sa) * 0.125f);
        _Float16 c2 = (_Float16)(expf(0.2f * sa) * 0.125f);
        unsigned short u1 = __builtin_bit_cast(unsigned short, c1);
        unsigned short u2 = __builtin_bit_cast(unsigned short, c2);
        Cc[(size_t)g * NN + n] = ((unsigned)u2 << 16) | (unsigned)u1;
    } else {
        int h = g - 8;
        Eh[(size_t)h * NN + n] = (_Float16)expf(sa);
        Fh[(size_t)h * NN + n] = (_Float16)expf(0.2f * sa);
    }
    {
        int row = tid >> 4, col0 = (tid & 15) * 8;
        const float* src = &xs[row][col0];
        f16x8 b0;
#pragma unroll
        for (int j = 0; j < 8; ++j) b0[j] = (_Float16)src[j];
        *(f16x8*)(xb + (size_t)(n0 + row) * FIN + col0) = b0;
    }
}

// ---------------- K2: Vt[h][f][n] = proj[h]^T @ x^T via fp16 MFMA
__global__ __launch_bounds__(256) void vt_kernel(
    const float* __restrict__ proj, const _Float16* __restrict__ xb,
    _Float16* __restrict__ Vt) {
    __shared__ _Float16 pT[FOUT][FIN + 8];
    const int tid = threadIdx.x;
    const int h = blockIdx.x >> 6;
    const int ng = blockIdx.x & 63;
    for (int idx = tid; idx < FIN * FOUT; idx += 256) {
        int i = idx >> 6, f = idx & 63;
        pT[f][i] = (_Float16)proj[(size_t)h * FIN * FOUT + idx];
    }
    __syncthreads();
    const int wave = tid >> 6, lane = tid & 63, q = lane >> 4, li = lane & 15;
    const int nb = ng * 64 + wave * 16;
    f32x4 acc[4];
#pragma unroll
    for (int n = 0; n < 4; ++n) acc[n] = (f32x4){0.f, 0.f, 0.f, 0.f};
#pragma unroll
    for (int kt = 0; kt < 4; ++kt) {
        f16x8 bfrag = *(const f16x8*)(xb + (size_t)(nb + li) * FIN + kt * 32 + q * 8);
#pragma unroll
        for (int ft = 0; ft < 4; ++ft) {
            f16x8 afrag = *(const f16x8*)&pT[ft * 16 + li][kt * 32 + q * 8];
            acc[ft] = __builtin_amdgcn_mfma_f32_16x16x32_f16(afrag, bfrag, acc[ft], 0, 0, 0);
        }
    }
#pragma unroll
    for (int ft = 0; ft < 4; ++ft)
#pragma unroll
        for (int reg = 0; reg < 4; ++reg)
            Vt[((size_t)h * FOUT + ft * 16 + q * 4 + reg) * NN + nb + li] = (_Float16)acc[ft][reg];
}

// ---------------- K3: attention, SHARED-head blocks (R4 schedule, proven), now at
// 5 blocks/CU: maskS stride 18 -> 16 words with XOR-swizzled word index
// (col ^ (row&7)) so the stride-16 layout stays conflict-free (lanes li, li+8 share
// a column -> same bank at different rows = free 2-way). LDS = 16KB mask + 16KB vbuf
// = 32768B exactly -> 5 blocks/CU (was 4). Schedule/DMA/vmcnt identical to R4:
// per-body vmcnt(4) drains {DMA(kt), EF(kt)} issued 1-2 bodies earlier; raw s_barrier
// publishes buffer kt%4. Tail mask prefetch (i=7, dead values) reads <=64B past maskS
// into vbuf — in-block LDS, harmless.
__attribute__((amdgpu_waves_per_eu(5)))
__global__ __launch_bounds__(256) void attn_kernel(
    const u64* __restrict__ maskbits, const _Float16* __restrict__ Vtg,
    const _Float16* __restrict__ Ehg, const _Float16* __restrict__ Fhg,
    const unsigned* __restrict__ Ccg,
    __hip_bfloat16* __restrict__ accP, float* __restrict__ rsP) {
    __shared__ u64 maskS[4][32][16];      // 16 KB, XOR-swizzled columns
    __shared__ char vbuf[4][4096];        // 16 KB shared quad-buffer
    const int tid = threadIdx.x;
    const int w = tid >> 6;
    const int lane = tid & 63, q = lane >> 4, li = lane & 15;
    const int qt = blockIdx.x >> 5;       // 0..31
    const int ks = (blockIdx.x >> 3) & 3;
    const int h  = blockIdx.x & 7;        // XCD = h -> per-XCD V working set small
    const int row0 = qt * 128 + w * 32;   // this wave's 32 Q-rows
    const int kb0 = ks * 1024;

    const int r_ = lane >> 2;
    const int sg = ((lane & 3) - (r_ >> 1)) & 3;
    // wave w supplies f-rows w*16 + r_ of the shared tile (identity-composed swizzle)
    const _Float16* gsrc = Vtg + ((size_t)h * FOUT + w * 16 + r_) * NN + kb0 + sg * 8;
    const int rdoff = li * 64 + ((q + (li >> 1)) & 3) * 16;     // bytes within 4KB buf
    const _Float16* ehp = Ehg + (size_t)h * NN + kb0 + q * 8;
    const _Float16* fhp = Fhg + (size_t)h * NN + kb0 + q * 8;

#define DMA_TILE(B, OFF) \
    __builtin_amdgcn_global_load_lds( \
        (const __attribute__((address_space(1))) void*)(gsrc + (OFF)), \
        (__attribute__((address_space(3))) void*)&vbuf[B][w * 1024], 16, 0, 0)

    {   // stage this wave's 32 rows x 16 mask words (512 words, 8 per lane),
        // column XOR-swizzled by row&7 (matches read-side swizzle)
#pragma unroll
        for (int j = 0; j < 8; ++j) {
            int t = lane + j * 64;
            int r = t >> 4, c = t & 15;
            maskS[w][r][c ^ (r & 7)] =
                maskbits[(size_t)(row0 + r) * 64 + ks * 16 + c];
        }
    }
    // Prologue: EF(0) -> set 0; DMA chunks 0,1 into buffers 0,1.
    uint4 e0 = *(const uint4*)(ehp);
    uint4 f0 = *(const uint4*)(fhp);
    uint4 e1, f1;
    DMA_TILE(0, 0);
    DMA_TILE(1, 32);

    h2 c1h[2], c2h[2];
#pragma unroll
    for (int rt = 0; rt < 2; ++rt) {
        unsigned cw = Ccg[(size_t)h * NN + row0 + rt * 16 + li];
        c1h[rt] = as_h2((cw << 16) | (cw & 0xffffu));
        c2h[rt] = as_h2((cw >> 16) | (cw & 0xffff0000u));
    }
    __syncthreads();                      // drains all prologue VMEM; masks visible

    f16x8 ones;
#pragma unroll
    for (int j = 0; j < 8; ++j) ones[j] = (_Float16)1.0f;

    f32x4 acc[2][4];
    f32x4 rsacc[2];
#pragma unroll
    for (int rt = 0; rt < 2; ++rt) {
#pragma unroll
        for (int n = 0; n < 4; ++n) acc[rt][n] = (f32x4){0.f, 0.f, 0.f, 0.f};
        rsacc[rt] = (f32x4){0.f, 0.f, 0.f, 0.f};
    }

    const int sx = li & 7;                // read-side swizzle (same for row li, 16+li)
    const u64* mp0s = &maskS[w][li][0];
    const u64* mp1s = &maskS[w][16 + li][0];
    u64 ma0 = mp0s[0 ^ sx], ma1 = mp1s[0 ^ sx];   // mask words, chunk-pair 0
    u64 mb0 = mp0s[1 ^ sx], mb1 = mp1s[1 ^ sx];   // chunk-pair 1
    int wa = 2, wb = 3;                   // next pair indices to prefetch

// Body for kt = 4i + K2. Issue order: EF(kt+1) loads, then DMA(kt+2); the
// s_waitcnt vmcnt(4) drains exactly {DMA(kt), EF(kt)} (issued 1-2 bodies ago),
// leaving {DMA(kt+1), EF(kt+1), DMA(kt+2)} in flight. Raw s_barrier publishes
// buffer kt%4 (each wave has awaited its own DMA quarter).
#define BODY(K2, EU, FU, EN, FN, MW0, MW1) do {                                               \
    EN = *(const uint4*)(ehp + ((K2) + 1) * 32);                                              \
    FN = *(const uint4*)(fhp + ((K2) + 1) * 32);                                              \
    asm volatile("" ::: "memory");             /* pin EF prefetch before the DMA */           \
    DMA_TILE(((K2) + 2) & 3, ((K2) + 2) * 32);                                                \
    asm volatile("s_waitcnt vmcnt(4)" ::: "memory");                                          \
    __builtin_amdgcn_s_barrier();                                                             \
    f16x8 vf_[4];                                                                             \
    _Pragma("unroll")                                                                         \
    for (int n = 0; n < 4; ++n)                                                               \
        vf_[n] = *(const f16x8*)&vbuf[K2][n * 1024 + rdoff];                                  \
    unsigned ew_[4] = {EU.x, EU.y, EU.z, EU.w};                                               \
    unsigned fw_[4] = {FU.x, FU.y, FU.z, FU.w};                                               \
    _Pragma("unroll")                                                                         \
    for (int rt = 0; rt < 2; ++rt) {                                                          \
        u64 mw_ = rt ? (MW1) : (MW0);                                                         \
        unsigned mm_ = (unsigned)(mw_ >> (((K2) & 1) * 32 + q * 8)) & 0xffu;                  \
        unsigned mlo_ = mm_ & 0xFu, mhi_ = mm_ >> 4;                                          \
        unsigned blo_ = (mlo_ | (mlo_ << 7) | (mlo_ << 14) | (mlo_ << 21)) & 0x01010101u;     \
        unsigned bhi_ = (mhi_ | (mhi_ << 7) | (mhi_ << 14) | (mhi_ << 21)) & 0x01010101u;     \
        blo_ = (blo_ << 8) - blo_;                                                            \
        bhi_ = (bhi_ << 8) - bhi_;                                                            \
        unsigned mk_[4] = {__builtin_amdgcn_perm(0u, blo_, 0x01010000u),                      \
                           __builtin_amdgcn_perm(0u, blo_, 0x03030202u),                      \
                           __builtin_amdgcn_perm(0u, bhi_, 0x01010000u),                      \
                           __builtin_amdgcn_perm(0u, bhi_, 0x03030202u)};                     \
        union { f16x8 v; unsigned u[4]; } pf_;                                                \
        _Pragma("unroll")                                                                     \
        for (int j2 = 0; j2 < 4; ++j2) {                                                      \
            h2 t_ = c1h[rt] * as_h2(ew_[j2]);                                                 \
            h2 u_ = c2h[rt] * as_h2(fw_[j2]);                                                 \
            h2 p_ = __builtin_elementwise_max(t_, u_);                                        \
            pf_.u[j2] = as_u32(p_) & mk_[j2];                                                 \
        }                                                                                     \
        rsacc[rt] = __builtin_amdgcn_mfma_f32_16x16x32_f16(pf_.v, ones, rsacc[rt], 0, 0, 0);  \
        _Pragma("unroll")                                                                     \
        for (int n = 0; n < 4; ++n)                                                           \
            acc[rt][n] = __builtin_amdgcn_mfma_f32_16x16x32_f16(pf_.v, vf_[n], acc[rt][n],    \
                                                                0, 0, 0);                     \
    }                                                                                         \
} while (0)

#pragma unroll 1
    for (int i = 0; i < 8; ++i) {         // 4 chunks (128 keys) per iteration
        // prefetch next two chunk-pairs' mask words (swizzled index; dead at i=7)
        u64 na0 = mp0s[wa ^ sx], na1 = mp1s[wa ^ sx];
        u64 nb0 = mp0s[wb ^ sx], nb1 = mp1s[wb ^ sx];
        BODY(0, e0, f0, e1, f1, ma0, ma1);
        BODY(1, e1, f1, e0, f0, ma0, ma1);
        BODY(2, e0, f0, e1, f1, mb0, mb1);
        BODY(3, e1, f1, e0, f0, mb0, mb1);
        ma0 = na0; ma1 = na1; mb0 = nb0; mb1 = nb1;
        wa += 2; wb += 2;
        gsrc += 128; ehp += 128; fhp += 128;
    }
#undef BODY
#undef DMA_TILE

    asm volatile("s_waitcnt vmcnt(0)" ::: "memory");   // drain tail over-prefetches

#pragma unroll
    for (int rt = 0; rt < 2; ++rt) {
        if (li == 0) {
#pragma unroll
            for (int reg = 0; reg < 4; ++reg)
                rsP[(size_t)(ks * NH + h) * NN + row0 + rt * 16 + q * 4 + reg] = rsacc[rt][reg];
        }
        __hip_bfloat16* ap = accP + ((size_t)(ks * NH + h) * NN + row0 + rt * 16) * 64;
#pragma unroll
        for (int n = 0; n < 4; ++n)
#pragma unroll
            for (int reg = 0; reg < 4; ++reg)
                ap[(q * 4 + reg) * 64 + n * 16 + li] = __float2bfloat16(acc[rt][n][reg]);
    }
}

// ---------------- K4: combine k-split partials + mean heads + skip + LeakyReLU.
// Vectorized: each thread owns 4 consecutive f (uint2 loads = 8B/lane, float4 store).
__global__ __launch_bounds__(256) void combine_kernel(
    const __hip_bfloat16* __restrict__ accP, const float* __restrict__ rsP,
    float* __restrict__ out) {
    int idx = blockIdx.x * 256 + threadIdx.x;      // 65536 = 4096 rows x 16 groups
    int row = idx >> 4, fg = (idx & 15) * 4;
    float s0 = 0.f, s1 = 0.f, s2 = 0.f, s3 = 0.f;
#pragma unroll 1
    for (int h = 0; h < NH; ++h) {
        float a0 = 0.f, a1 = 0.f, a2 = 0.f, a3 = 0.f, r = 0.f;
#pragma unroll
        for (int k = 0; k < KS; ++k) {
            const __hip_bfloat16* p = accP + ((size_t)(k * NH + h) * NN + row) * 64 + fg;
            uint2 v = *(const uint2*)p;
            a0 += __uint_as_float(v.x << 16);
            a1 += __uint_as_float(v.x & 0xffff0000u);
            a2 += __uint_as_float(v.y << 16);
            a3 += __uint_as_float(v.y & 0xffff0000u);
            r  += rsP[(size_t)(k * NH + h) * NN + row];
        }
        float ir = 1.0f / r;
        s0 += a0 * ir; s1 += a1 * ir; s2 += a2 * ir; s3 += a3 * ir;
    }
    float4 o = *(float4*)(out + (size_t)row * 64 + fg);    // currently holds skipm
    float v0 = s0 * 0.125f + o.x, v1 = s1 * 0.125f + o.y;
    float v2 = s2 * 0.125f + o.z, v3 = s3 * 0.125f + o.w;
    o.x = fmaxf(v0, 0.2f * v0); o.y = fmaxf(v1, 0.2f * v1);
    o.z = fmaxf(v2, 0.2f * v2); o.w = fmaxf(v3, 0.2f * v3);
    *(float4*)(out + (size_t)row * 64 + fg) = o;
}

extern "C" void kernel_launch(void* const* d_in, const int* in_sizes, int n_in,
                              void* d_out, int out_size, void* d_ws, size_t ws_size,
                              hipStream_t stream) {
    (void)in_sizes; (void)n_in; (void)out_size; (void)ws_size;
    const float* x         = (const float*)d_in[0];   // [4096,128]
    const float* topology  = (const float*)d_in[1];   // [4096,4096]
    const float* proj      = (const float*)d_in[2];   // [8,128,64]
    const float* score_src = (const float*)d_in[3];   // [8,64]
    const float* score_dst = (const float*)d_in[4];   // [8,64]
    const float* skip_w    = (const float*)d_in[5];   // [512,128]
    float* out = (float*)d_out;                       // [4096,64]

    char* ws = (char*)d_ws;
    _Float16* xb   = (_Float16*)ws;                            // 1 MB
    _Float16* Vt   = (_Float16*)(ws + 1048576);                // 4 MB
    _Float16* Eh   = (_Float16*)(ws + 5242880);                // 64 KB
    _Float16* Fh   = (_Float16*)(ws + 5308416);                // 64 KB
    unsigned* Cc   = (unsigned*)(ws + 5373952);                // 128 KB
    float* Wc      = (float*)(ws + 5505024);                   // 40 KB
    u64* maskbits  = (u64*)(ws + 5545984);                     // 2 MB
    float* rsP     = (float*)(ws + 7643136);                   // 512 KB
    __hip_bfloat16* accP = (__hip_bfloat16*)(ws + 8167424);    // 16 MB (end ~24.9 MB)
    float* skipm = out;   // skip GEMM lives in d_out; combine consumes & overwrites

    maskwc_kernel<<<2088, 256, 0, stream>>>(topology, maskbits, proj, score_src,
                                            score_dst, skip_w, Wc);
    scores_kernel<<<256, 256, 0, stream>>>(x, Wc, skipm, Eh, Fh, Cc, xb);
    vt_kernel<<<512, 256, 0, stream>>>(proj, xb, Vt);
    attn_kernel<<<1024, 256, 0, stream>>>(maskbits, Vt, Eh, Fh, Cc, accP, rsP);
    combine_kernel<<<256, 256, 0, stream>>>(accP, rsP, out);
}

// Round 9
// 176.892 us; speedup vs baseline: 1.6427x; 1.6427x over previous
//
#include <hip/hip_runtime.h>
#include <hip/hip_bf16.h>

#define NN 4096
#define FIN 128
#define FOUT 64
#define NH 8
#define KS 4          // K splits (1024 keys per block)

typedef float f32x4 __attribute__((ext_vector_type(4)));
typedef _Float16 f16x8 __attribute__((ext_vector_type(8)));
typedef _Float16 h2 __attribute__((ext_vector_type(2)));
typedef unsigned long long u64;

static __device__ __forceinline__ h2 as_h2(unsigned u) { return __builtin_bit_cast(h2, u); }
static __device__ __forceinline__ unsigned as_u32(h2 v) { return __builtin_bit_cast(unsigned, v); }

// spread16->64: bit i -> bit 4i (scalar u64 ops -> SALU, off the VALU pipe)
static __device__ __forceinline__ u64 spread4(u64 x) {
    x = (x | (x << 24)) & 0x000000FF000000FFull;
    x = (x | (x << 12)) & 0x000F000F000F000Full;
    x = (x | (x << 6))  & 0x0303030303030303ull;
    x = (x | (x << 3))  & 0x1111111111111111ull;
    return x;
}

// ---------------- K0: fused mask + Wc. Mask role: float4 loads (16B/lane, peak-BW
// regime; stride 256 floats/iter = exactly the wave's read width), 4 ballots per iter,
// scalar bit-spread assembles 4 mask words. (Validated R6/R7.)
__global__ __launch_bounds__(256) void maskwc_kernel(
    const float* __restrict__ topo, u64* __restrict__ mb,
    const float* __restrict__ proj, const float* __restrict__ score_src,
    const float* __restrict__ score_dst, const float* __restrict__ skip_w,
    float* __restrict__ Wc) {
    const int tid = threadIdx.x;
    if (blockIdx.x < 2048) {               // ---- mask role
        const int wg = blockIdx.x * 4 + (tid >> 6);   // wave 0..8191
        const int lane = tid & 63;
        const size_t base = (size_t)wg * 32;          // 32 mask words per wave
        const float* tp = topo + base * 64 + lane * 4;
#pragma unroll
        for (int it = 0; it < 8; ++it) {
            float4 v = *(const float4*)(tp + it * 256);    // 256 floats per wave-iter
            u64 b0 = __ballot(v.x > -0.5e9f);
            u64 b1 = __ballot(v.y > -0.5e9f);
            u64 b2 = __ballot(v.z > -0.5e9f);
            u64 b3 = __ballot(v.w > -0.5e9f);
            // word g (lanes 16g..16g+15): bit 4*li+c = bc[16g+li]
            u64 wv[4];
#pragma unroll
            for (int g = 0; g < 4; ++g) {
                u64 x0 = spread4((b0 >> (16 * g)) & 0xFFFFu);
                u64 x1 = spread4((b1 >> (16 * g)) & 0xFFFFu);
                u64 x2 = spread4((b2 >> (16 * g)) & 0xFFFFu);
                u64 x3 = spread4((b3 >> (16 * g)) & 0xFFFFu);
                wv[g] = x0 | (x1 << 1) | (x2 << 2) | (x3 << 3);
            }
            if (lane == 0) {
                ulonglong2 s01; s01.x = wv[0]; s01.y = wv[1];
                ulonglong2 s23; s23.x = wv[2]; s23.y = wv[3];
                *(ulonglong2*)&mb[base + it * 4] = s01;
                *(ulonglong2*)&mb[base + it * 4 + 2] = s23;
            }
        }
        return;
    }
    // ---- wc role
    int idx = (blockIdx.x - 2048) * 256 + tid;
    if (idx >= FIN * 80) return;
    int i = idx / 80, c = idx % 80;
    float v = 0.f;
    if (c < 16) {
        int h = c & 7;
        const float* w = (c < 8 ? score_src : score_dst) + h * FOUT;
        const float* p = proj + (size_t)h * FIN * FOUT + (size_t)i * FOUT;
        for (int f = 0; f < FOUT; ++f) v += p[f] * w[f];
    } else {
        int f = c - 16;
        for (int h = 0; h < NH; ++h) v += skip_w[(size_t)(h * FOUT + f) * FIN + i];
        v *= 0.125f;
    }
    Wc[i * 80 + c] = v;
}

// ---------------- K1: x@Wc -> skipm (in d_out), E/F fp16 planes, Cc packed fp16, xb fp16
// C1,C2 pre-scaled by 1/8 (per-row constant, cancels exactly in the softmax ratio) so
// all fp16 products C1*E, C2*F stay far below 65504 (bound ~600 at 1.5x sigma margin).
__global__ __launch_bounds__(256) void scores_kernel(
    const float* __restrict__ x, const float* __restrict__ Wc,
    float* __restrict__ skipm, _Float16* __restrict__ Eh, _Float16* __restrict__ Fh,
    unsigned* __restrict__ Cc, _Float16* __restrict__ xb) {
    __shared__ float wcs[FIN][80];
    __shared__ float xs[16][FIN + 5];
    const int n0 = blockIdx.x * 16;
    const int tid = threadIdx.x;
    for (int i = tid; i < FIN * 80 / 4; i += 256)
        ((float4*)&wcs[0][0])[i] = ((const float4*)Wc)[i];
    const float4* xsrc = (const float4*)(x + (size_t)n0 * FIN);
    for (int i = tid; i < 16 * FIN / 4; i += 256) {
        int r = i >> 5, c4 = i & 31;
        *(float4*)&xs[r][c4 * 4] = xsrc[i];
    }
    __syncthreads();
    const int r = tid & 15;
    const int g = tid >> 4;
    float acc[4];
    float sa = 0.f;
#pragma unroll
    for (int j = 0; j < 4; ++j) acc[j] = 0.f;
#pragma unroll 4
    for (int i = 0; i < FIN; ++i) {
        float xv = xs[r][i];
        float4 p = *(float4*)&wcs[i][16 + g * 4];
        float qv = wcs[i][g];
        acc[0] += xv * p.x; acc[1] += xv * p.y; acc[2] += xv * p.z; acc[3] += xv * p.w;
        sa += xv * qv;
    }
    int n = n0 + r;
#pragma unroll
    for (int j = 0; j < 4; ++j) skipm[(size_t)n * FOUT + g * 4 + j] = acc[j];
    if (g < 8) {
        _Float16 c1 = (_Float16)(expf(sa) * 0.125f);
        _Float16 c2 = (_Float16)(expf(0.2f * sa) * 0.125f);
        unsigned short u1 = __builtin_bit_cast(unsigned short, c1);
        unsigned short u2 = __builtin_bit_cast(unsigned short, c2);
        Cc[(size_t)g * NN + n] = ((unsigned)u2 << 16) | (unsigned)u1;
    } else {
        int h = g - 8;
        Eh[(size_t)h * NN + n] = (_Float16)expf(sa);
        Fh[(size_t)h * NN + n] = (_Float16)expf(0.2f * sa);
    }
    {
        int row = tid >> 4, col0 = (tid & 15) * 8;
        const float* src = &xs[row][col0];
        f16x8 b0;
#pragma unroll
        for (int j = 0; j < 8; ++j) b0[j] = (_Float16)src[j];
        *(f16x8*)(xb + (size_t)(n0 + row) * FIN + col0) = b0;
    }
}

// ---------------- K2: Vt[h][f][n] = proj[h]^T @ x^T via fp16 MFMA
__global__ __launch_bounds__(256) void vt_kernel(
    const float* __restrict__ proj, const _Float16* __restrict__ xb,
    _Float16* __restrict__ Vt) {
    __shared__ _Float16 pT[FOUT][FIN + 8];
    const int tid = threadIdx.x;
    const int h = blockIdx.x >> 6;
    const int ng = blockIdx.x & 63;
    for (int idx = tid; idx < FIN * FOUT; idx += 256) {
        int i = idx >> 6, f = idx & 63;
        pT[f][i] = (_Float16)proj[(size_t)h * FIN * FOUT + idx];
    }
    __syncthreads();
    const int wave = tid >> 6, lane = tid & 63, q = lane >> 4, li = lane & 15;
    const int nb = ng * 64 + wave * 16;
    f32x4 acc[4];
#pragma unroll
    for (int n = 0; n < 4; ++n) acc[n] = (f32x4){0.f, 0.f, 0.f, 0.f};
#pragma unroll
    for (int kt = 0; kt < 4; ++kt) {
        f16x8 bfrag = *(const f16x8*)(xb + (size_t)(nb + li) * FIN + kt * 32 + q * 8);
#pragma unroll
        for (int ft = 0; ft < 4; ++ft) {
            f16x8 afrag = *(const f16x8*)&pT[ft * 16 + li][kt * 32 + q * 8];
            acc[ft] = __builtin_amdgcn_mfma_f32_16x16x32_f16(afrag, bfrag, acc[ft], 0, 0, 0);
        }
    }
#pragma unroll
    for (int ft = 0; ft < 4; ++ft)
#pragma unroll
        for (int reg = 0; reg < 4; ++reg)
            Vt[((size_t)h * FOUT + ft * 16 + q * 4 + reg) * NN + nb + li] = (_Float16)acc[ft][reg];
}

// ---------------- K3: attention, SHARED-head blocks (R4 schedule, proven 41.3us in R7).
// Block = 1 head x 128 Q-rows (4 waves x 32 rows). The 4KB V-chunk is staged ONCE per
// block into a shared LDS quad-buffer: each wave DMAs its own 1KB quarter (wave w
// supplies f-rows w*16..+15, identity-composed swizzle with c=w), then a raw s_barrier
// publishes it. Quad-buffer + depth-2 prefetch: the per-body s_waitcnt vmcnt(4) leaves
// {DMA(k+1), EF(k+1), DMA(k+2)} in flight, draining only ops issued >=1-2 full bodies
// earlier. WAR safety: buffer k%4 is overwritten by DMAs issued after the barrier that
// follows its last read.
// CLOSED AXES (measured): R2/R6 schedule surgery regressed; R3 direct-load transport
// regressed; R8 waves_per_eu(5) spilled accumulators to scratch (VGPR cap 96 < ~128
// needed -> 650MB scratch traffic, 155us). Occupancy is register-bound at 4 waves/SIMD;
// keep waves_per_eu(4) and stride-18 maskS.
__attribute__((amdgpu_waves_per_eu(4)))
__global__ __launch_bounds__(256) void attn_kernel(
    const u64* __restrict__ maskbits, const _Float16* __restrict__ Vtg,
    const _Float16* __restrict__ Ehg, const _Float16* __restrict__ Fhg,
    const unsigned* __restrict__ Ccg,
    __hip_bfloat16* __restrict__ accP, float* __restrict__ rsP) {
    __shared__ u64 maskS[4][32][18];      // 18.4 KB (stride 18 words = conflict-free)
    __shared__ char vbuf[4][4096];        // 16 KB shared quad-buffer
    const int tid = threadIdx.x;
    const int w = tid >> 6;
    const int lane = tid & 63, q = lane >> 4, li = lane & 15;
    const int qt = blockIdx.x >> 5;       // 0..31
    const int ks = (blockIdx.x >> 3) & 3;
    const int h  = blockIdx.x & 7;        // XCD = h -> per-XCD V working set small
    const int row0 = qt * 128 + w * 32;   // this wave's 32 Q-rows
    const int kb0 = ks * 1024;

    const int r_ = lane >> 2;
    const int sg = ((lane & 3) - (r_ >> 1)) & 3;
    // wave w supplies f-rows w*16 + r_ of the shared tile (identity-composed swizzle)
    const _Float16* gsrc = Vtg + ((size_t)h * FOUT + w * 16 + r_) * NN + kb0 + sg * 8;
    const int rdoff = li * 64 + ((q + (li >> 1)) & 3) * 16;     // bytes within 4KB buf
    const _Float16* ehp = Ehg + (size_t)h * NN + kb0 + q * 8;
    const _Float16* fhp = Fhg + (size_t)h * NN + kb0 + q * 8;

#define DMA_TILE(B, OFF) \
    __builtin_amdgcn_global_load_lds( \
        (const __attribute__((address_space(1))) void*)(gsrc + (OFF)), \
        (__attribute__((address_space(3))) void*)&vbuf[B][w * 1024], 16, 0, 0)

    {   // stage this wave's 32 rows x 16 mask words (512 words, 8 per lane)
#pragma unroll
        for (int j = 0; j < 8; ++j) {
            int t = lane + j * 64;
            maskS[w][t >> 4][t & 15] =
                maskbits[(size_t)(row0 + (t >> 4)) * 64 + ks * 16 + (t & 15)];
        }
    }
    // Prologue: EF(0) -> set 0; DMA chunks 0,1 into buffers 0,1.
    uint4 e0 = *(const uint4*)(ehp);
    uint4 f0 = *(const uint4*)(fhp);
    uint4 e1, f1;
    DMA_TILE(0, 0);
    DMA_TILE(1, 32);

    h2 c1h[2], c2h[2];
#pragma unroll
    for (int rt = 0; rt < 2; ++rt) {
        unsigned cw = Ccg[(size_t)h * NN + row0 + rt * 16 + li];
        c1h[rt] = as_h2((cw << 16) | (cw & 0xffffu));
        c2h[rt] = as_h2((cw >> 16) | (cw & 0xffff0000u));
    }
    __syncthreads();                      // drains all prologue VMEM; masks visible

    f16x8 ones;
#pragma unroll
    for (int j = 0; j < 8; ++j) ones[j] = (_Float16)1.0f;

    f32x4 acc[2][4];
    f32x4 rsacc[2];
#pragma unroll
    for (int rt = 0; rt < 2; ++rt) {
#pragma unroll
        for (int n = 0; n < 4; ++n) acc[rt][n] = (f32x4){0.f, 0.f, 0.f, 0.f};
        rsacc[rt] = (f32x4){0.f, 0.f, 0.f, 0.f};
    }

    const u64* mp0 = &maskS[w][li][0];
    const u64* mp1 = &maskS[w][16 + li][0];
    u64 ma0 = mp0[0], ma1 = mp1[0];       // mask words, chunk-pair 0
    u64 mb0 = mp0[1], mb1 = mp1[1];       // chunk-pair 1

// Body for kt = 4i + K2. Issue order: EF(kt+1) loads, then DMA(kt+2); the
// s_waitcnt vmcnt(4) drains exactly {DMA(kt), EF(kt)} (issued 1-2 bodies ago),
// leaving {DMA(kt+1), EF(kt+1), DMA(kt+2)} in flight. Raw s_barrier publishes
// buffer kt%4 (each wave has awaited its own DMA quarter).
#define BODY(K2, EU, FU, EN, FN, MW0, MW1) do {                                               \
    EN = *(const uint4*)(ehp + ((K2) + 1) * 32);                                              \
    FN = *(const uint4*)(fhp + ((K2) + 1) * 32);                                              \
    asm volatile("" ::: "memory");             /* pin EF prefetch before the DMA */           \
    DMA_TILE(((K2) + 2) & 3, ((K2) + 2) * 32);                                                \
    asm volatile("s_waitcnt vmcnt(4)" ::: "memory");                                          \
    __builtin_amdgcn_s_barrier();                                                             \
    f16x8 vf_[4];                                                                             \
    _Pragma("unroll")                                                                         \
    for (int n = 0; n < 4; ++n)                                                               \
        vf_[n] = *(const f16x8*)&vbuf[K2][n * 1024 + rdoff];                                  \
    unsigned ew_[4] = {EU.x, EU.y, EU.z, EU.w};                                               \
    unsigned fw_[4] = {FU.x, FU.y, FU.z, FU.w};                                               \
    _Pragma("unroll")                                                                         \
    for (int rt = 0; rt < 2; ++rt) {                                                          \
        u64 mw_ = rt ? (MW1) : (MW0);                                                         \
        unsigned mm_ = (unsigned)(mw_ >> (((K2) & 1) * 32 + q * 8)) & 0xffu;                  \
        unsigned mlo_ = mm_ & 0xFu, mhi_ = mm_ >> 4;                                          \
        unsigned blo_ = (mlo_ | (mlo_ << 7) | (mlo_ << 14) | (mlo_ << 21)) & 0x01010101u;     \
        unsigned bhi_ = (mhi_ | (mhi_ << 7) | (mhi_ << 14) | (mhi_ << 21)) & 0x01010101u;     \
        blo_ = (blo_ << 8) - blo_;                                                            \
        bhi_ = (bhi_ << 8) - bhi_;                                                            \
        unsigned mk_[4] = {__builtin_amdgcn_perm(0u, blo_, 0x01010000u),                      \
                           __builtin_amdgcn_perm(0u, blo_, 0x03030202u),                      \
                           __builtin_amdgcn_perm(0u, bhi_, 0x01010000u),                      \
                           __builtin_amdgcn_perm(0u, bhi_, 0x03030202u)};                     \
        union { f16x8 v; unsigned u[4]; } pf_;                                                \
        _Pragma("unroll")                                                                     \
        for (int j2 = 0; j2 < 4; ++j2) {                                                      \
            h2 t_ = c1h[rt] * as_h2(ew_[j2]);                                                 \
            h2 u_ = c2h[rt] * as_h2(fw_[j2]);                                                 \
            h2 p_ = __builtin_elementwise_max(t_, u_);                                        \
            pf_.u[j2] = as_u32(p_) & mk_[j2];                                                 \
        }                                                                                     \
        rsacc[rt] = __builtin_amdgcn_mfma_f32_16x16x32_f16(pf_.v, ones, rsacc[rt], 0, 0, 0);  \
        _Pragma("unroll")                                                                     \
        for (int n = 0; n < 4; ++n)                                                           \
            acc[rt][n] = __builtin_amdgcn_mfma_f32_16x16x32_f16(pf_.v, vf_[n], acc[rt][n],    \
                                                                0, 0, 0);                     \
    }                                                                                         \
} while (0)

#pragma unroll 1
    for (int i = 0; i < 8; ++i) {         // 4 chunks (128 keys) per iteration
        u64 na0 = mp0[2], na1 = mp1[2];   // prefetch next two chunk-pairs' mask words
        u64 nb0 = mp0[3], nb1 = mp1[3];
        BODY(0, e0, f0, e1, f1, ma0, ma1);
        BODY(1, e1, f1, e0, f0, ma0, ma1);
        BODY(2, e0, f0, e1, f1, mb0, mb1);
        BODY(3, e1, f1, e0, f0, mb0, mb1);
        ma0 = na0; ma1 = na1; mb0 = nb0; mb1 = nb1;
        mp0 += 2; mp1 += 2;
        gsrc += 128; ehp += 128; fhp += 128;
    }
#undef BODY
#undef DMA_TILE

    asm volatile("s_waitcnt vmcnt(0)" ::: "memory");   // drain tail over-prefetches

#pragma unroll
    for (int rt = 0; rt < 2; ++rt) {
        if (li == 0) {
#pragma unroll
            for (int reg = 0; reg < 4; ++reg)
                rsP[(size_t)(ks * NH + h) * NN + row0 + rt * 16 + q * 4 + reg] = rsacc[rt][reg];
        }
        __hip_bfloat16* ap = accP + ((size_t)(ks * NH + h) * NN + row0 + rt * 16) * 64;
#pragma unroll
        for (int n = 0; n < 4; ++n)
#pragma unroll
            for (int reg = 0; reg < 4; ++reg)
                ap[(q * 4 + reg) * 64 + n * 16 + li] = __float2bfloat16(acc[rt][n][reg]);
    }
}

// ---------------- K4: combine k-split partials + mean heads + skip + LeakyReLU.
// Vectorized: each thread owns 4 consecutive f (uint2 loads = 8B/lane, float4 store).
__global__ __launch_bounds__(256) void combine_kernel(
    const __hip_bfloat16* __restrict__ accP, const float* __restrict__ rsP,
    float* __restrict__ out) {
    int idx = blockIdx.x * 256 + threadIdx.x;      // 65536 = 4096 rows x 16 groups
    int row = idx >> 4, fg = (idx & 15) * 4;
    float s0 = 0.f, s1 = 0.f, s2 = 0.f, s3 = 0.f;
#pragma unroll 1
    for (int h = 0; h < NH; ++h) {
        float a0 = 0.f, a1 = 0.f, a2 = 0.f, a3 = 0.f, r = 0.f;
#pragma unroll
        for (int k = 0; k < KS; ++k) {
            const __hip_bfloat16* p = accP + ((size_t)(k * NH + h) * NN + row) * 64 + fg;
            uint2 v = *(const uint2*)p;
            a0 += __uint_as_float(v.x << 16);
            a1 += __uint_as_float(v.x & 0xffff0000u);
            a2 += __uint_as_float(v.y << 16);
            a3 += __uint_as_float(v.y & 0xffff0000u);
            r  += rsP[(size_t)(k * NH + h) * NN + row];
        }
        float ir = 1.0f / r;
        s0 += a0 * ir; s1 += a1 * ir; s2 += a2 * ir; s3 += a3 * ir;
    }
    float4 o = *(float4*)(out + (size_t)row * 64 + fg);    // currently holds skipm
    float v0 = s0 * 0.125f + o.x, v1 = s1 * 0.125f + o.y;
    float v2 = s2 * 0.125f + o.z, v3 = s3 * 0.125f + o.w;
    o.x = fmaxf(v0, 0.2f * v0); o.y = fmaxf(v1, 0.2f * v1);
    o.z = fmaxf(v2, 0.2f * v2); o.w = fmaxf(v3, 0.2f * v3);
    *(float4*)(out + (size_t)row * 64 + fg) = o;
}

extern "C" void kernel_launch(void* const* d_in, const int* in_sizes, int n_in,
                              void* d_out, int out_size, void* d_ws, size_t ws_size,
                              hipStream_t stream) {
    (void)in_sizes; (void)n_in; (void)out_size; (void)ws_size;
    const float* x         = (const float*)d_in[0];   // [4096,128]
    const float* topology  = (const float*)d_in[1];   // [4096,4096]
    const float* proj      = (const float*)d_in[2];   // [8,128,64]
    const float* score_src = (const float*)d_in[3];   // [8,64]
    const float* score_dst = (const float*)d_in[4];   // [8,64]
    const float* skip_w    = (const float*)d_in[5];   // [512,128]
    float* out = (float*)d_out;                       // [4096,64]

    char* ws = (char*)d_ws;
    _Float16* xb   = (_Float16*)ws;                            // 1 MB
    _Float16* Vt   = (_Float16*)(ws + 1048576);                // 4 MB
    _Float16* Eh   = (_Float16*)(ws + 5242880);                // 64 KB
    _Float16* Fh   = (_Float16*)(ws + 5308416);                // 64 KB
    unsigned* Cc   = (unsigned*)(ws + 5373952);                // 128 KB
    float* Wc      = (float*)(ws + 5505024);                   // 40 KB
    u64* maskbits  = (u64*)(ws + 5545984);                     // 2 MB
    float* rsP     = (float*)(ws + 7643136);                   // 512 KB
    __hip_bfloat16* accP = (__hip_bfloat16*)(ws + 8167424);    // 16 MB (end ~24.9 MB)
    float* skipm = out;   // skip GEMM lives in d_out; combine consumes & overwrites

    maskwc_kernel<<<2088, 256, 0, stream>>>(topology, maskbits, proj, score_src,
                                            score_dst, skip_w, Wc);
    scores_kernel<<<256, 256, 0, stream>>>(x, Wc, skipm, Eh, Fh, Cc, xb);
    vt_kernel<<<512, 256, 0, stream>>>(proj, xb, Vt);
    attn_kernel<<<1024, 256, 0, stream>>>(maskbits, Vt, Eh, Fh, Cc, accP, rsP);
    combine_kernel<<<256, 256, 0, stream>>>(accP, rsP, out);
}

// Round 10
// 173.368 us; speedup vs baseline: 1.6761x; 1.0203x over previous
//
#include <hip/hip_runtime.h>
#include <hip/hip_bf16.h>

#define NN 4096
#define FIN 128
#define FOUT 64
#define NH 8
#define KS 4          // K splits (1024 keys per block)

typedef float f32x4 __attribute__((ext_vector_type(4)));
typedef _Float16 f16x8 __attribute__((ext_vector_type(8)));
typedef _Float16 h2 __attribute__((ext_vector_type(2)));
typedef unsigned long long u64;

static __device__ __forceinline__ h2 as_h2(unsigned u) { return __builtin_bit_cast(h2, u); }
static __device__ __forceinline__ unsigned as_u32(h2 v) { return __builtin_bit_cast(unsigned, v); }

// spread16->64: bit i -> bit 4i (scalar u64 ops -> SALU, off the VALU pipe)
static __device__ __forceinline__ u64 spread4(u64 x) {
    x = (x | (x << 24)) & 0x000000FF000000FFull;
    x = (x | (x << 12)) & 0x000F000F000F000Full;
    x = (x | (x << 6))  & 0x0303030303030303ull;
    x = (x | (x << 3))  & 0x1111111111111111ull;
    return x;
}

// ---------------- K0: fused mask + Wc. Mask role: float4 loads (16B/lane, peak-BW
// regime; stride 256 floats/iter = exactly the wave's read width), 4 ballots per iter,
// scalar bit-spread assembles 4 mask words. (Validated R6/R7.)
__global__ __launch_bounds__(256) void maskwc_kernel(
    const float* __restrict__ topo, u64* __restrict__ mb,
    const float* __restrict__ proj, const float* __restrict__ score_src,
    const float* __restrict__ score_dst, const float* __restrict__ skip_w,
    float* __restrict__ Wc) {
    const int tid = threadIdx.x;
    if (blockIdx.x < 2048) {               // ---- mask role
        const int wg = blockIdx.x * 4 + (tid >> 6);   // wave 0..8191
        const int lane = tid & 63;
        const size_t base = (size_t)wg * 32;          // 32 mask words per wave
        const float* tp = topo + base * 64 + lane * 4;
#pragma unroll
        for (int it = 0; it < 8; ++it) {
            float4 v = *(const float4*)(tp + it * 256);    // 256 floats per wave-iter
            u64 b0 = __ballot(v.x > -0.5e9f);
            u64 b1 = __ballot(v.y > -0.5e9f);
            u64 b2 = __ballot(v.z > -0.5e9f);
            u64 b3 = __ballot(v.w > -0.5e9f);
            // word g (lanes 16g..16g+15): bit 4*li+c = bc[16g+li]
            u64 wv[4];
#pragma unroll
            for (int g = 0; g < 4; ++g) {
                u64 x0 = spread4((b0 >> (16 * g)) & 0xFFFFu);
                u64 x1 = spread4((b1 >> (16 * g)) & 0xFFFFu);
                u64 x2 = spread4((b2 >> (16 * g)) & 0xFFFFu);
                u64 x3 = spread4((b3 >> (16 * g)) & 0xFFFFu);
                wv[g] = x0 | (x1 << 1) | (x2 << 2) | (x3 << 3);
            }
            if (lane == 0) {
                ulonglong2 s01; s01.x = wv[0]; s01.y = wv[1];
                ulonglong2 s23; s23.x = wv[2]; s23.y = wv[3];
                *(ulonglong2*)&mb[base + it * 4] = s01;
                *(ulonglong2*)&mb[base + it * 4 + 2] = s23;
            }
        }
        return;
    }
    // ---- wc role
    int idx = (blockIdx.x - 2048) * 256 + tid;
    if (idx >= FIN * 80) return;
    int i = idx / 80, c = idx % 80;
    float v = 0.f;
    if (c < 16) {
        int h = c & 7;
        const float* w = (c < 8 ? score_src : score_dst) + h * FOUT;
        const float* p = proj + (size_t)h * FIN * FOUT + (size_t)i * FOUT;
        for (int f = 0; f < FOUT; ++f) v += p[f] * w[f];
    } else {
        int f = c - 16;
        for (int h = 0; h < NH; ++h) v += skip_w[(size_t)(h * FOUT + f) * FIN + i];
        v *= 0.125f;
    }
    Wc[i * 80 + c] = v;
}

// ---------------- K1: x@Wc -> skipm (in d_out), E/F fp16 planes, Cc packed fp16, xb fp16
// C1,C2 pre-scaled by 1/8 (per-row constant, cancels exactly in the softmax ratio) so
// all fp16 products C1*E, C2*F stay far below 65504 (bound ~600 at 1.5x sigma margin).
__global__ __launch_bounds__(256) void scores_kernel(
    const float* __restrict__ x, const float* __restrict__ Wc,
    float* __restrict__ skipm, _Float16* __restrict__ Eh, _Float16* __restrict__ Fh,
    unsigned* __restrict__ Cc, _Float16* __restrict__ xb) {
    __shared__ float wcs[FIN][80];
    __shared__ float xs[16][FIN + 5];
    const int n0 = blockIdx.x * 16;
    const int tid = threadIdx.x;
    for (int i = tid; i < FIN * 80 / 4; i += 256)
        ((float4*)&wcs[0][0])[i] = ((const float4*)Wc)[i];
    const float4* xsrc = (const float4*)(x + (size_t)n0 * FIN);
    for (int i = tid; i < 16 * FIN / 4; i += 256) {
        int r = i >> 5, c4 = i & 31;
        *(float4*)&xs[r][c4 * 4] = xsrc[i];
    }
    __syncthreads();
    const int r = tid & 15;
    const int g = tid >> 4;
    float acc[4];
    float sa = 0.f;
#pragma unroll
    for (int j = 0; j < 4; ++j) acc[j] = 0.f;
#pragma unroll 4
    for (int i = 0; i < FIN; ++i) {
        float xv = xs[r][i];
        float4 p = *(float4*)&wcs[i][16 + g * 4];
        float qv = wcs[i][g];
        acc[0] += xv * p.x; acc[1] += xv * p.y; acc[2] += xv * p.z; acc[3] += xv * p.w;
        sa += xv * qv;
    }
    int n = n0 + r;
#pragma unroll
    for (int j = 0; j < 4; ++j) skipm[(size_t)n * FOUT + g * 4 + j] = acc[j];
    if (g < 8) {
        _Float16 c1 = (_Float16)(expf(sa) * 0.125f);
        _Float16 c2 = (_Float16)(expf(0.2f * sa) * 0.125f);
        unsigned short u1 = __builtin_bit_cast(unsigned short, c1);
        unsigned short u2 = __builtin_bit_cast(unsigned short, c2);
        Cc[(size_t)g * NN + n] = ((unsigned)u2 << 16) | (unsigned)u1;
    } else {
        int h = g - 8;
        Eh[(size_t)h * NN + n] = (_Float16)expf(sa);
        Fh[(size_t)h * NN + n] = (_Float16)expf(0.2f * sa);
    }
    {
        int row = tid >> 4, col0 = (tid & 15) * 8;
        const float* src = &xs[row][col0];
        f16x8 b0;
#pragma unroll
        for (int j = 0; j < 8; ++j) b0[j] = (_Float16)src[j];
        *(f16x8*)(xb + (size_t)(n0 + row) * FIN + col0) = b0;
    }
}

// ---------------- K2: Vt[h][f][n] = proj[h]^T @ x^T via fp16 MFMA
__global__ __launch_bounds__(256) void vt_kernel(
    const float* __restrict__ proj, const _Float16* __restrict__ xb,
    _Float16* __restrict__ Vt) {
    __shared__ _Float16 pT[FOUT][FIN + 8];
    const int tid = threadIdx.x;
    const int h = blockIdx.x >> 6;
    const int ng = blockIdx.x & 63;
    for (int idx = tid; idx < FIN * FOUT; idx += 256) {
        int i = idx >> 6, f = idx & 63;
        pT[f][i] = (_Float16)proj[(size_t)h * FIN * FOUT + idx];
    }
    __syncthreads();
    const int wave = tid >> 6, lane = tid & 63, q = lane >> 4, li = lane & 15;
    const int nb = ng * 64 + wave * 16;
    f32x4 acc[4];
#pragma unroll
    for (int n = 0; n < 4; ++n) acc[n] = (f32x4){0.f, 0.f, 0.f, 0.f};
#pragma unroll
    for (int kt = 0; kt < 4; ++kt) {
        f16x8 bfrag = *(const f16x8*)(xb + (size_t)(nb + li) * FIN + kt * 32 + q * 8);
#pragma unroll
        for (int ft = 0; ft < 4; ++ft) {
            f16x8 afrag = *(const f16x8*)&pT[ft * 16 + li][kt * 32 + q * 8];
            acc[ft] = __builtin_amdgcn_mfma_f32_16x16x32_f16(afrag, bfrag, acc[ft], 0, 0, 0);
        }
    }
#pragma unroll
    for (int ft = 0; ft < 4; ++ft)
#pragma unroll
        for (int reg = 0; reg < 4; ++reg)
            Vt[((size_t)h * FOUT + ft * 16 + q * 4 + reg) * NN + nb + li] = (_Float16)acc[ft][reg];
}

// ---------------- K3: attention, SHARED-head blocks, 64 Q-ROWS PER WAVE.
// The V-tile stream depends only on (ks,h) — identical for every qt — so doubling each
// wave's Q-rows (32->64; block covers 256 rows; grid 1024->512) doubles per-body compute
// (20 MFMA + ~100 VALU) against the SAME 3 VMEM ops/body: the R4/R7 vmcnt(4) schedule is
// byte-identical, the per-body stall is amortized over 2x work, and V L2 traffic halves.
// Resident waves ~8/CU vs the ~9 measured before (occupancy plateaued there anyway).
// waves_per_eu(2): accumulator file is now ~170 regs — capping at 4 waves/EU would spill
// (R8's 650MB-scratch failure mode); 2 blocks/CU by grid, so 2 waves/EU is the truth.
// CLOSED AXES (measured): R2/R6 schedule surgery; R3 direct-load transport; R8 5-block
// occupancy (register-bound).
__attribute__((amdgpu_waves_per_eu(2)))
__global__ __launch_bounds__(256) void attn_kernel(
    const u64* __restrict__ maskbits, const _Float16* __restrict__ Vtg,
    const _Float16* __restrict__ Ehg, const _Float16* __restrict__ Fhg,
    const unsigned* __restrict__ Ccg,
    __hip_bfloat16* __restrict__ accP, float* __restrict__ rsP) {
    __shared__ u64 maskS[4][64][18];      // 36.9 KB (stride 18 words = conflict-free)
    __shared__ char vbuf[4][4096];        // 16 KB shared quad-buffer
    const int tid = threadIdx.x;
    const int w = tid >> 6;
    const int lane = tid & 63, q = lane >> 4, li = lane & 15;
    const int qt = blockIdx.x >> 5;       // 0..15
    const int ks = (blockIdx.x >> 3) & 3;
    const int h  = blockIdx.x & 7;        // XCD = h -> per-XCD V working set small
    const int row0 = qt * 256 + w * 64;   // this wave's 64 Q-rows
    const int kb0 = ks * 1024;

    const int r_ = lane >> 2;
    const int sg = ((lane & 3) - (r_ >> 1)) & 3;
    // wave w supplies f-rows w*16 + r_ of the shared tile (identity-composed swizzle)
    const _Float16* gsrc = Vtg + ((size_t)h * FOUT + w * 16 + r_) * NN + kb0 + sg * 8;
    const int rdoff = li * 64 + ((q + (li >> 1)) & 3) * 16;     // bytes within 4KB buf
    const _Float16* ehp = Ehg + (size_t)h * NN + kb0 + q * 8;
    const _Float16* fhp = Fhg + (size_t)h * NN + kb0 + q * 8;

#define DMA_TILE(B, OFF) \
    __builtin_amdgcn_global_load_lds( \
        (const __attribute__((address_space(1))) void*)(gsrc + (OFF)), \
        (__attribute__((address_space(3))) void*)&vbuf[B][w * 1024], 16, 0, 0)

    {   // stage this wave's 64 rows x 16 mask words (1024 words, 16 per lane)
#pragma unroll
        for (int j = 0; j < 16; ++j) {
            int t = lane + j * 64;
            maskS[w][t >> 4][t & 15] =
                maskbits[(size_t)(row0 + (t >> 4)) * 64 + ks * 16 + (t & 15)];
        }
    }
    // Prologue: EF(0) -> set 0; DMA chunks 0,1 into buffers 0,1.
    uint4 e0 = *(const uint4*)(ehp);
    uint4 f0 = *(const uint4*)(fhp);
    uint4 e1, f1;
    DMA_TILE(0, 0);
    DMA_TILE(1, 32);

    h2 c1h[4], c2h[4];
#pragma unroll
    for (int rt = 0; rt < 4; ++rt) {
        unsigned cw = Ccg[(size_t)h * NN + row0 + rt * 16 + li];
        c1h[rt] = as_h2((cw << 16) | (cw & 0xffffu));
        c2h[rt] = as_h2((cw >> 16) | (cw & 0xffff0000u));
    }
    __syncthreads();                      // drains all prologue VMEM; masks visible

    f16x8 ones;
#pragma unroll
    for (int j = 0; j < 8; ++j) ones[j] = (_Float16)1.0f;

    f32x4 acc[4][4];
    f32x4 rsacc[4];
#pragma unroll
    for (int rt = 0; rt < 4; ++rt) {
#pragma unroll
        for (int n = 0; n < 4; ++n) acc[rt][n] = (f32x4){0.f, 0.f, 0.f, 0.f};
        rsacc[rt] = (f32x4){0.f, 0.f, 0.f, 0.f};
    }

    const u64* mp0 = &maskS[w][li][0];
    const u64* mp1 = &maskS[w][16 + li][0];
    const u64* mp2 = &maskS[w][32 + li][0];
    const u64* mp3 = &maskS[w][48 + li][0];
    u64 ma0 = mp0[0], ma1 = mp1[0], ma2 = mp2[0], ma3 = mp3[0];   // word for bodies 0,1
    u64 mb0 = mp0[1], mb1 = mp1[1], mb2 = mp2[1], mb3 = mp3[1];   // word for bodies 2,3

// Body for kt = 4i + K2. Issue order: EF(kt+1) loads, then DMA(kt+2); the
// s_waitcnt vmcnt(4) drains exactly {DMA(kt), EF(kt)} (issued 1-2 bodies ago),
// leaving {DMA(kt+1), EF(kt+1), DMA(kt+2)} in flight. Raw s_barrier publishes
// buffer kt%4 (each wave has awaited its own DMA quarter).
#define BODY(K2, EU, FU, EN, FN, M0, M1, M2, M3) do {                                         \
    EN = *(const uint4*)(ehp + ((K2) + 1) * 32);                                              \
    FN = *(const uint4*)(fhp + ((K2) + 1) * 32);                                              \
    asm volatile("" ::: "memory");             /* pin EF prefetch before the DMA */           \
    DMA_TILE(((K2) + 2) & 3, ((K2) + 2) * 32);                                                \
    asm volatile("s_waitcnt vmcnt(4)" ::: "memory");                                          \
    __builtin_amdgcn_s_barrier();                                                             \
    f16x8 vf_[4];                                                                             \
    _Pragma("unroll")                                                                         \
    for (int n = 0; n < 4; ++n)                                                               \
        vf_[n] = *(const f16x8*)&vbuf[K2][n * 1024 + rdoff];                                  \
    unsigned ew_[4] = {EU.x, EU.y, EU.z, EU.w};                                               \
    unsigned fw_[4] = {FU.x, FU.y, FU.z, FU.w};                                               \
    _Pragma("unroll")                                                                         \
    for (int rt = 0; rt < 4; ++rt) {                                                          \
        u64 mw_ = (rt == 0) ? (M0) : (rt == 1) ? (M1) : (rt == 2) ? (M2) : (M3);              \
        unsigned mm_ = (unsigned)(mw_ >> (((K2) & 1) * 32 + q * 8)) & 0xffu;                  \
        unsigned mlo_ = mm_ & 0xFu, mhi_ = mm_ >> 4;                                          \
        unsigned blo_ = (mlo_ | (mlo_ << 7) | (mlo_ << 14) | (mlo_ << 21)) & 0x01010101u;     \
        unsigned bhi_ = (mhi_ | (mhi_ << 7) | (mhi_ << 14) | (mhi_ << 21)) & 0x01010101u;     \
        blo_ = (blo_ << 8) - blo_;                                                            \
        bhi_ = (bhi_ << 8) - bhi_;                                                            \
        unsigned mk_[4] = {__builtin_amdgcn_perm(0u, blo_, 0x01010000u),                      \
                           __builtin_amdgcn_perm(0u, blo_, 0x03030202u),                      \
                           __builtin_amdgcn_perm(0u, bhi_, 0x01010000u),                      \
                           __builtin_amdgcn_perm(0u, bhi_, 0x03030202u)};                     \
        union { f16x8 v; unsigned u[4]; } pf_;                                                \
        _Pragma("unroll")                                                                     \
        for (int j2 = 0; j2 < 4; ++j2) {                                                      \
            h2 t_ = c1h[rt] * as_h2(ew_[j2]);                                                 \
            h2 u_ = c2h[rt] * as_h2(fw_[j2]);                                                 \
            h2 p_ = __builtin_elementwise_max(t_, u_);                                        \
            pf_.u[j2] = as_u32(p_) & mk_[j2];                                                 \
        }                                                                                     \
        rsacc[rt] = __builtin_amdgcn_mfma_f32_16x16x32_f16(pf_.v, ones, rsacc[rt], 0, 0, 0);  \
        _Pragma("unroll")                                                                     \
        for (int n = 0; n < 4; ++n)                                                           \
            acc[rt][n] = __builtin_amdgcn_mfma_f32_16x16x32_f16(pf_.v, vf_[n], acc[rt][n],    \
                                                                0, 0, 0);                     \
    }                                                                                         \
} while (0)

#pragma unroll 1
    for (int i = 0; i < 8; ++i) {         // 4 chunks (128 keys) per iteration
        // prefetch next two chunk-pairs' mask words (i=7 reads pad words 16,17)
        u64 na0 = mp0[2], na1 = mp1[2], na2 = mp2[2], na3 = mp3[2];
        u64 nb0 = mp0[3], nb1 = mp1[3], nb2 = mp2[3], nb3 = mp3[3];
        BODY(0, e0, f0, e1, f1, ma0, ma1, ma2, ma3);
        BODY(1, e1, f1, e0, f0, ma0, ma1, ma2, ma3);
        BODY(2, e0, f0, e1, f1, mb0, mb1, mb2, mb3);
        BODY(3, e1, f1, e0, f0, mb0, mb1, mb2, mb3);
        ma0 = na0; ma1 = na1; ma2 = na2; ma3 = na3;
        mb0 = nb0; mb1 = nb1; mb2 = nb2; mb3 = nb3;
        mp0 += 2; mp1 += 2; mp2 += 2; mp3 += 2;
        gsrc += 128; ehp += 128; fhp += 128;
    }
#undef BODY
#undef DMA_TILE

    asm volatile("s_waitcnt vmcnt(0)" ::: "memory");   // drain tail over-prefetches

#pragma unroll
    for (int rt = 0; rt < 4; ++rt) {
        if (li == 0) {
#pragma unroll
            for (int reg = 0; reg < 4; ++reg)
                rsP[(size_t)(ks * NH + h) * NN + row0 + rt * 16 + q * 4 + reg] = rsacc[rt][reg];
        }
        __hip_bfloat16* ap = accP + ((size_t)(ks * NH + h) * NN + row0 + rt * 16) * 64;
#pragma unroll
        for (int n = 0; n < 4; ++n)
#pragma unroll
            for (int reg = 0; reg < 4; ++reg)
                ap[(q * 4 + reg) * 64 + n * 16 + li] = __float2bfloat16(acc[rt][n][reg]);
    }
}

// ---------------- K4: combine k-split partials + mean heads + skip + LeakyReLU.
// Vectorized: each thread owns 4 consecutive f (uint2 loads = 8B/lane, float4 store).
__global__ __launch_bounds__(256) void combine_kernel(
    const __hip_bfloat16* __restrict__ accP, const float* __restrict__ rsP,
    float* __restrict__ out) {
    int idx = blockIdx.x * 256 + threadIdx.x;      // 65536 = 4096 rows x 16 groups
    int row = idx >> 4, fg = (idx & 15) * 4;
    float s0 = 0.f, s1 = 0.f, s2 = 0.f, s3 = 0.f;
#pragma unroll 1
    for (int h = 0; h < NH; ++h) {
        float a0 = 0.f, a1 = 0.f, a2 = 0.f, a3 = 0.f, r = 0.f;
#pragma unroll
        for (int k = 0; k < KS; ++k) {
            const __hip_bfloat16* p = accP + ((size_t)(k * NH + h) * NN + row) * 64 + fg;
            uint2 v = *(const uint2*)p;
            a0 += __uint_as_float(v.x << 16);
            a1 += __uint_as_float(v.x & 0xffff0000u);
            a2 += __uint_as_float(v.y << 16);
            a3 += __uint_as_float(v.y & 0xffff0000u);
            r  += rsP[(size_t)(k * NH + h) * NN + row];
        }
        float ir = 1.0f / r;
        s0 += a0 * ir; s1 += a1 * ir; s2 += a2 * ir; s3 += a3 * ir;
    }
    float4 o = *(float4*)(out + (size_t)row * 64 + fg);    // currently holds skipm
    float v0 = s0 * 0.125f + o.x, v1 = s1 * 0.125f + o.y;
    float v2 = s2 * 0.125f + o.z, v3 = s3 * 0.125f + o.w;
    o.x = fmaxf(v0, 0.2f * v0); o.y = fmaxf(v1, 0.2f * v1);
    o.z = fmaxf(v2, 0.2f * v2); o.w = fmaxf(v3, 0.2f * v3);
    *(float4*)(out + (size_t)row * 64 + fg) = o;
}

extern "C" void kernel_launch(void* const* d_in, const int* in_sizes, int n_in,
                              void* d_out, int out_size, void* d_ws, size_t ws_size,
                              hipStream_t stream) {
    (void)in_sizes; (void)n_in; (void)out_size; (void)ws_size;
    const float* x         = (const float*)d_in[0];   // [4096,128]
    const float* topology  = (const float*)d_in[1];   // [4096,4096]
    const float* proj      = (const float*)d_in[2];   // [8,128,64]
    const float* score_src = (const float*)d_in[3];   // [8,64]
    const float* score_dst = (const float*)d_in[4];   // [8,64]
    const float* skip_w    = (const float*)d_in[5];   // [512,128]
    float* out = (float*)d_out;                       // [4096,64]

    char* ws = (char*)d_ws;
    _Float16* xb   = (_Float16*)ws;                            // 1 MB
    _Float16* Vt   = (_Float16*)(ws + 1048576);                // 4 MB
    _Float16* Eh   = (_Float16*)(ws + 5242880);                // 64 KB
    _Float16* Fh   = (_Float16*)(ws + 5308416);                // 64 KB
    unsigned* Cc   = (unsigned*)(ws + 5373952);                // 128 KB
    float* Wc      = (float*)(ws + 5505024);                   // 40 KB
    u64* maskbits  = (u64*)(ws + 5545984);                     // 2 MB
    float* rsP     = (float*)(ws + 7643136);                   // 512 KB
    __hip_bfloat16* accP = (__hip_bfloat16*)(ws + 8167424);    // 16 MB (end ~24.9 MB)
    float* skipm = out;   // skip GEMM lives in d_out; combine consumes & overwrites

    maskwc_kernel<<<2088, 256, 0, stream>>>(topology, maskbits, proj, score_src,
                                            score_dst, skip_w, Wc);
    scores_kernel<<<256, 256, 0, stream>>>(x, Wc, skipm, Eh, Fh, Cc, xb);
    vt_kernel<<<512, 256, 0, stream>>>(proj, xb, Vt);
    attn_kernel<<<512, 256, 0, stream>>>(maskbits, Vt, Eh, Fh, Cc, accP, rsP);
    combine_kernel<<<256, 256, 0, stream>>>(accP, rsP, out);
}